// Round 4
// baseline (391.607 us; speedup 1.0000x reference)
//
#include <hip/hip_runtime.h>

#define HH 256
#define WW 256
#define BATCH 8
#define CH 64
#define NIMG (BATCH*CH)      // 512
#define HWSZ (HH*WW)         // 65536
#define SCL (1.0f/12.0f)
#define KH 0.04f
#define TFRAC 0.7f
#define RS 16                // rows per thread-tile in K1
#define NEGINF (-__builtin_inff())

// K1: register-rolling Harris. Thread = 4 cols x RS rows; one wave = full
// 256-col row slab, column halos via lane shuffles. Software pipeline:
// raw loads run 2-3 iterations ahead, shuffle-expansion runs 1 iteration
// ahead of consumption (4-slot im ring), so neither global-load latency nor
// ds_bpermute latency sits on the per-iteration critical path. VGPR=92 was
// rounding to the 128 granule anyway -> the extra ~12 regs of pipeline state
// are free (launch_bounds caps at 128 to stay in-band).
__global__ __launch_bounds__(256, 4) void k1(const float* __restrict__ x,
                                             float* __restrict__ rv,
                                             float* __restrict__ ms)
{
    const int tid = threadIdx.x;
    const int img = blockIdx.x >> 2;                     // 4 blocks per image
    const int tx  = tid & 63;                            // col chunk (4 cols)
    const int sy  = ((blockIdx.x & 3) << 2) | (tid >> 6);// row slab 0..15 (wave-uniform)
    const int r0  = sy * RS;
    const int c0  = tx * 4;
    const float* ib = x + (size_t)img * HWSZ;
    float* rb = rv + (size_t)img * HWSZ;

    float im[4][8];                        // expanded img rows ring (row r0-3+j -> slot j&3)
    float hx[3][4], hq[3][4], hy[3][4];    // horizontal 3-sums of products
    float R[3][4];                         // R rows window, cols c0..c0+3
    float rmax = NEGINF;

    auto loadraw = [&](int gr) -> float4 {
        gr = gr < 0 ? -gr : (gr >= HH ? 2*HH - 2 - gr : gr);   // reflect101
        return *(const float4*)(ib + gr * WW + c0);
    };
    auto expand = [&](float4 own, float* d) {
        float upz = __shfl_up(own.z, 1);     // lane-1 col 4l-2
        float upw = __shfl_up(own.w, 1);     // lane-1 col 4l-1
        float dnx = __shfl_down(own.x, 1);   // lane+1 col 4l+4
        float dny = __shfl_down(own.y, 1);   // lane+1 col 4l+5
        d[0] = (tx > 0)  ? upz : own.z;      // col -2 -> reflect 2
        d[1] = (tx > 0)  ? upw : own.y;      // col -1 -> reflect 1
        d[2] = own.x; d[3] = own.y; d[4] = own.z; d[5] = own.w;
        d[6] = (tx < 63) ? dnx : own.z;      // col 256 -> reflect 254
        d[7] = (tx < 63) ? dny : own.y;      // col 257 -> reflect 253
    };

    // prologue: rows r0-3..r0-1 expanded; raw0 = row r0, raw1 = row r0+1
    expand(loadraw(r0 - 3), im[0]);
    expand(loadraw(r0 - 2), im[1]);
    expand(loadraw(r0 - 1), im[2]);
    float4 raw0 = loadraw(r0);
    float4 raw1 = loadraw(r0 + 1);

    // invariant at top of iter i: raw0 = row r0+i, raw1 = row r0+i+1,
    // rows r0+i-3..r0+i-1 expanded in slots i&3,(i+1)&3,(i+2)&3.
#pragma unroll
    for (int i = 0; i < RS + 4; ++i) {
        const int m = r0 - 2 + i;          // product-row index this step

        // expand row r0+i into slot (i+3)&3 -- consumed NEXT iteration.
        if (i <= RS + 2) expand(raw0, im[(i + 3) & 3]);
        raw0 = raw1;
        if (i <= RS) raw1 = loadraw(r0 + i + 2);   // 2-deep prefetch

        // products row m from img rows m-1,m,m+1; fold to horizontal 3-sums
        {
            const int ia = i & 3, ib2 = (i + 1) & 3, ic = (i + 2) & 3;
            float t1[8], t2[8];
#pragma unroll
            for (int q = 0; q < 8; ++q) {
                t1[q] = im[ia][q] + 2.0f * im[ib2][q] + im[ic][q];
                t2[q] = im[ic][q] - im[ia][q];
            }
            float pxv[6], pqv[6], pyv[6];
#pragma unroll
            for (int q = 0; q < 6; ++q) {
                float dx = SCL * (t1[q + 2] - t1[q]);
                float dy = SCL * (t2[q] + 2.0f * t2[q + 1] + t2[q + 2]);
                pxv[q] = dx * dx;
                pqv[q] = dx * dy;
                pyv[q] = dy * dy;
            }
            // Box stage reflects the product FIELD: pxy(-1) = +pxy(1), but
            // recomputing from the reflected image gives -pxy(1) (dx odd, dy
            // even under column reflection). pxx/pyy are even -> already OK.
            if (tx == 0)  pqv[0] = -pqv[0];   // col -1
            if (tx == 63) pqv[5] = -pqv[5];   // col 256
            const int po = i % 3;
#pragma unroll
            for (int j = 0; j < 4; ++j) {
                hx[po][j] = pxv[j] + pxv[j + 1] + pxv[j + 2];
                hq[po][j] = pqv[j] + pqv[j + 1] + pqv[j + 2];
                hy[po][j] = pyv[j] + pyv[j + 1] + pyv[j + 2];
            }
        }

        // R row s = m-1 (h rows s-1,s,s+1 at slots (i+1)%3,(i+2)%3,i%3)
        if (i >= 2) {
            const int s = m - 1;
            const int A = (i + 1) % 3, B2 = (i + 2) % 3, C2 = i % 3;
            const bool vs = (s >= 0) && (s < HH);   // wave-uniform
#pragma unroll
            for (int j = 0; j < 4; ++j) {
                float ixx, ixy, iyy;
                if (s == 0) {            // product-field reflect: S(0)=p0+2*p1
                    ixx = hx[B2][j] + 2.0f * hx[C2][j];
                    ixy = hq[B2][j] + 2.0f * hq[C2][j];
                    iyy = hy[B2][j] + 2.0f * hy[C2][j];
                } else if (s == HH - 1) { // S(255)=2*p254+p255
                    ixx = 2.0f * hx[A][j] + hx[B2][j];
                    ixy = 2.0f * hq[A][j] + hq[B2][j];
                    iyy = 2.0f * hy[A][j] + hy[B2][j];
                } else {
                    ixx = hx[A][j] + hx[B2][j] + hx[C2][j];
                    ixy = hq[A][j] + hq[B2][j] + hq[C2][j];
                    iyy = hy[A][j] + hy[B2][j] + hy[C2][j];
                }
                float tr = ixx + iyy;
                float Rj = (ixx * iyy - ixy * ixy) - KH * tr * tr;
                Rj = vs ? Rj : NEGINF;
                R[i % 3][j] = Rj;
                rmax = fmaxf(rmax, Rj);
            }
        }

        // Rv row r = m-2 (R rows r-1,r,r+1 at slots (i+1)%3,(i+2)%3,i%3)
        if (i >= 4) {
            const int r = r0 - 4 + i;       // in [r0, r0+RS-1]
            const int A = (i + 1) % 3, B2 = (i + 2) % 3, C2 = i % 3;
            float4 o;
            o.x = fmaxf(fmaxf(R[A][0], R[B2][0]), R[C2][0]);
            o.y = fmaxf(fmaxf(R[A][1], R[B2][1]), R[C2][1]);
            o.z = fmaxf(fmaxf(R[A][2], R[B2][2]), R[C2][2]);
            o.w = fmaxf(fmaxf(R[A][3], R[B2][3]), R[C2][3]);
            *(float4*)(rb + r * WW + c0) = o;
        }
    }

    // per-slab max: block = exactly 4 slabs of one image, plain store
#pragma unroll
    for (int off = 32; off; off >>= 1) rmax = fmaxf(rmax, __shfl_xor(rmax, off));
    __shared__ float sm[4];
    if ((tid & 63) == 0) sm[tid >> 6] = rmax;
    __syncthreads();
    if (tid == 0) {
        float mm = fmaxf(fmaxf(sm[0], sm[1]), fmaxf(sm[2], sm[3]));
        ms[(img << 2) | (blockIdx.x & 3)] = mm;
    }
}

// K2: block = one (b,h) row, 512 threads / 8 waves. Xl staged via
// global_load_lds; weights via the scalar path (wave-uniform SGPR index);
// 66 KB LDS -> 2 blocks/CU. Epilogue rv loads are issued BEFORE the barrier
// so they drain concurrently with the LDS DMA (the barrier's vmcnt(0) covers
// both), and their data is consumed only after the 2048-FMA GEMV.
__global__ __launch_bounds__(512, 4) void k2(const float* __restrict__ x,
                                             const float* __restrict__ wgt,
                                             const float* __restrict__ bias,
                                             const float* __restrict__ ms,
                                             float* __restrict__ io)
{
    __shared__ __align__(16) float Xl[CH][WW];   // 64 KiB
    __shared__ float tmax[CH];
    const int tid = threadIdx.x;
    const int wv  = tid >> 6;        // wave 0..7
    const int l   = tid & 63;        // lane 0..63
    const int b   = blockIdx.x >> 8;
    const int h   = blockIdx.x & 255;
    const int oc0 = __builtin_amdgcn_readfirstlane(wv << 3);  // SGPR: wave's first out-ch

    // ---- stage x row-block into LDS via async DMA; thresholds into LDS ----
    {
        const float* xrow = x + (size_t)b * CH * HWSZ + (size_t)h * WW + (l << 2);
#pragma unroll
        for (int k = 0; k < 8; ++k) {
            __builtin_amdgcn_global_load_lds(
                (const __attribute__((address_space(1))) unsigned int*)(xrow + (size_t)(oc0 + k) * HWSZ),
                (__attribute__((address_space(3))) unsigned int*)&Xl[oc0 + k][0],
                16, 0, 0);
        }
        if (tid < CH) {
            float4 m4 = *(const float4*)(ms + ((b * CH + tid) << 2));
            tmax[tid] = TFRAC * fmaxf(fmaxf(m4.x, m4.y), fmaxf(m4.z, m4.w));
        }
    }

    // ---- issue epilogue rv loads early: drain overlaps the LDS DMA ----
    const size_t pb = (size_t)b * CH * HWSZ + (size_t)h * WW + (size_t)(l << 2);
    float4 rvv[8];
#pragma unroll
    for (int j = 0; j < 8; ++j)
        rvv[j] = *(const float4*)(io + pb + (size_t)(oc0 + j) * HWSZ);

    __syncthreads();

    // ---- conv1x1: acc[j][k] = bias + sum_ci W[oc0+j][ci] * x[ci][4l+k] ----
    float acc[8][4];
#pragma unroll
    for (int j = 0; j < 8; ++j) {
        const float bj = bias[oc0 + j];
        acc[j][0] = bj; acc[j][1] = bj; acc[j][2] = bj; acc[j][3] = bj;
    }
#pragma unroll 2
    for (int c4 = 0; c4 < CH; c4 += 4) {
        const float4 xa = *(const float4*)&Xl[c4][l << 2];
        const float4 xb = *(const float4*)&Xl[c4 + 1][l << 2];
        const float4 xc = *(const float4*)&Xl[c4 + 2][l << 2];
        const float4 xd = *(const float4*)&Xl[c4 + 3][l << 2];
#pragma unroll
        for (int j = 0; j < 8; ++j) {
            const float4 wj = *(const float4*)(wgt + (oc0 + j) * CH + c4);  // scalar load
            acc[j][0] = fmaf(wj.x, xa.x, acc[j][0]);
            acc[j][1] = fmaf(wj.x, xa.y, acc[j][1]);
            acc[j][2] = fmaf(wj.x, xa.z, acc[j][2]);
            acc[j][3] = fmaf(wj.x, xa.w, acc[j][3]);
            acc[j][0] = fmaf(wj.y, xb.x, acc[j][0]);
            acc[j][1] = fmaf(wj.y, xb.y, acc[j][1]);
            acc[j][2] = fmaf(wj.y, xb.z, acc[j][2]);
            acc[j][3] = fmaf(wj.y, xb.w, acc[j][3]);
            acc[j][0] = fmaf(wj.z, xc.x, acc[j][0]);
            acc[j][1] = fmaf(wj.z, xc.y, acc[j][1]);
            acc[j][2] = fmaf(wj.z, xc.z, acc[j][2]);
            acc[j][3] = fmaf(wj.z, xc.w, acc[j][3]);
            acc[j][0] = fmaf(wj.w, xd.x, acc[j][0]);
            acc[j][1] = fmaf(wj.w, xd.y, acc[j][1]);
            acc[j][2] = fmaf(wj.w, xd.z, acc[j][2]);
            acc[j][3] = fmaf(wj.w, xd.w, acc[j][3]);
        }
    }

    // ---- epilogue: horizontal dilate of Rv + threshold + combine ----
#pragma unroll
    for (int j = 0; j < 8; ++j) {
        const int c = oc0 + j;
        float lf = __shfl_up(rvv[j].w, 1);
        float rt = __shfl_down(rvv[j].x, 1);
        if (l == 0)  lf = NEGINF;    // col -1: border does not contribute
        if (l == 63) rt = NEGINF;    // col 256
        const float d0 = fmaxf(fmaxf(lf,       rvv[j].x), rvv[j].y);
        const float d1 = fmaxf(fmaxf(rvv[j].x, rvv[j].y), rvv[j].z);
        const float d2 = fmaxf(fmaxf(rvv[j].y, rvv[j].z), rvv[j].w);
        const float d3 = fmaxf(fmaxf(rvv[j].z, rvv[j].w), rt);
        const float t = tmax[c];
        const float4 xi = *(const float4*)&Xl[c][l << 2];
        const float y0 = fmaxf(acc[j][0], 0.0f);
        const float y1 = fmaxf(acc[j][1], 0.0f);
        const float y2 = fmaxf(acc[j][2], 0.0f);
        const float y3 = fmaxf(acc[j][3], 0.0f);
        float4 o;
        o.x = fmaf(d0 > t ? 1.0f : (d0 < t ? 0.0f : xi.x), y0, xi.x);
        o.y = fmaf(d1 > t ? 1.0f : (d1 < t ? 0.0f : xi.y), y1, xi.y);
        o.z = fmaf(d2 > t ? 1.0f : (d2 < t ? 0.0f : xi.z), y2, xi.z);
        o.w = fmaf(d3 > t ? 1.0f : (d3 < t ? 0.0f : xi.w), y3, xi.w);
        *(float4*)(io + pb + (size_t)c * HWSZ) = o;
    }
}

extern "C" void kernel_launch(void* const* d_in, const int* in_sizes, int n_in,
                              void* d_out, int out_size, void* d_ws, size_t ws_size,
                              hipStream_t stream)
{
    const float* x    = (const float*)d_in[0];
    const float* wgt  = (const float*)d_in[1];
    const float* bias = (const float*)d_in[2];
    float* out = (float*)d_out;
    float* ms = (float*)d_ws;        // NIMG*4 slab maxima (8 KiB)

    hipLaunchKernelGGL(k1, dim3(NIMG * 4), dim3(256), 0, stream, x, out, ms);
    hipLaunchKernelGGL(k2, dim3(BATCH * HH), dim3(512), 0, stream,
                       x, wgt, bias, ms, out);
}

// Round 5
// 309.227 us; speedup vs baseline: 1.2664x; 1.2664x over previous
//
#include <hip/hip_runtime.h>

#define HH 256
#define WW 256
#define BATCH 8
#define CH 64
#define NIMG (BATCH*CH)      // 512
#define HWSZ (HH*WW)         // 65536
#define SCL (1.0f/12.0f)
#define KH 0.04f
#define TFRAC 0.7f
#define RS 16                // rows per thread-tile in K1
#define NEGINF (-__builtin_inff())

// K1: register-rolling Harris. Thread = 4 cols x RS rows; one wave = full
// 256-col row slab, column halos via lane shuffles. Pipeline: raw load runs
// 1 iteration ahead of its shuffle-expansion, expansion runs 1 iteration
// ahead of consumption (4-slot im ring) -> neither global-load latency nor
// ds_bpermute latency sits on the per-iteration critical path.
// NOTE: no __launch_bounds__ min-waves here. Round-4 evidence: (256,4) made
// the allocator target the 64-VGPR granule -> full pipeline state spilled to
// scratch (WRITE_SIZE 131->308 MB, dur 85->152 us). ~100 VGPRs live; the 128
// band (4 waves/SIMD) is the correct operating point.
__global__ __launch_bounds__(256) void k1(const float* __restrict__ x,
                                          float* __restrict__ rv,
                                          float* __restrict__ ms)
{
    const int tid = threadIdx.x;
    const int img = blockIdx.x >> 2;                     // 4 blocks per image
    const int tx  = tid & 63;                            // col chunk (4 cols)
    const int sy  = ((blockIdx.x & 3) << 2) | (tid >> 6);// row slab 0..15 (wave-uniform)
    const int r0  = sy * RS;
    const int c0  = tx * 4;
    const float* ib = x + (size_t)img * HWSZ;
    float* rb = rv + (size_t)img * HWSZ;

    float im[4][8];                        // expanded img rows ring
    float hx[3][4], hq[3][4], hy[3][4];    // horizontal 3-sums of products
    float R[3][4];                         // R rows window, cols c0..c0+3
    float rmax = NEGINF;

    auto loadraw = [&](int gr) -> float4 {
        gr = gr < 0 ? -gr : (gr >= HH ? 2*HH - 2 - gr : gr);   // reflect101
        return *(const float4*)(ib + gr * WW + c0);
    };
    auto expand = [&](float4 own, float* d) {
        float upz = __shfl_up(own.z, 1);     // lane-1 col 4l-2
        float upw = __shfl_up(own.w, 1);     // lane-1 col 4l-1
        float dnx = __shfl_down(own.x, 1);   // lane+1 col 4l+4
        float dny = __shfl_down(own.y, 1);   // lane+1 col 4l+5
        d[0] = (tx > 0)  ? upz : own.z;      // col -2 -> reflect 2
        d[1] = (tx > 0)  ? upw : own.y;      // col -1 -> reflect 1
        d[2] = own.x; d[3] = own.y; d[4] = own.z; d[5] = own.w;
        d[6] = (tx < 63) ? dnx : own.z;      // col 256 -> reflect 254
        d[7] = (tx < 63) ? dny : own.y;      // col 257 -> reflect 253
    };

    // prologue: rows r0-3..r0-1 expanded in slots 0,1,2; raw = row r0
    expand(loadraw(r0 - 3), im[0]);
    expand(loadraw(r0 - 2), im[1]);
    expand(loadraw(r0 - 1), im[2]);
    float4 raw = loadraw(r0);

    // invariant at top of iter i (product row m = r0-2+i): rows m-1,m,m+1
    // expanded in slots i&3,(i+1)&3,(i+2)&3; raw = row m+2 (= r0+i).
#pragma unroll
    for (int i = 0; i < RS + 4; ++i) {
        const int m = r0 - 2 + i;          // product-row index this step

        // expand row r0+i (consumed NEXT iteration); prefetch row r0+i+1
        if (i <= RS + 2) expand(raw, im[(i + 3) & 3]);
        if (i <= RS + 1) raw = loadraw(r0 + i + 1);

        // products row m from img rows m-1,m,m+1; fold to horizontal 3-sums
        {
            const int ia = i & 3, ib2 = (i + 1) & 3, ic = (i + 2) & 3;
            float t1[8], t2[8];
#pragma unroll
            for (int q = 0; q < 8; ++q) {
                t1[q] = im[ia][q] + 2.0f * im[ib2][q] + im[ic][q];
                t2[q] = im[ic][q] - im[ia][q];
            }
            float pxv[6], pqv[6], pyv[6];
#pragma unroll
            for (int q = 0; q < 6; ++q) {
                float dx = SCL * (t1[q + 2] - t1[q]);
                float dy = SCL * (t2[q] + 2.0f * t2[q + 1] + t2[q + 2]);
                pxv[q] = dx * dx;
                pqv[q] = dx * dy;
                pyv[q] = dy * dy;
            }
            // Box stage reflects the product FIELD: pxy(-1) = +pxy(1), but
            // recomputing from the reflected image gives -pxy(1) (dx odd, dy
            // even under column reflection). pxx/pyy are even -> already OK.
            if (tx == 0)  pqv[0] = -pqv[0];   // col -1
            if (tx == 63) pqv[5] = -pqv[5];   // col 256
            const int po = i % 3;
#pragma unroll
            for (int j = 0; j < 4; ++j) {
                hx[po][j] = pxv[j] + pxv[j + 1] + pxv[j + 2];
                hq[po][j] = pqv[j] + pqv[j + 1] + pqv[j + 2];
                hy[po][j] = pyv[j] + pyv[j + 1] + pyv[j + 2];
            }
        }

        // R row s = m-1 (h rows s-1,s,s+1 at slots (i+1)%3,(i+2)%3,i%3)
        if (i >= 2) {
            const int s = m - 1;
            const int A = (i + 1) % 3, B2 = (i + 2) % 3, C2 = i % 3;
            const bool vs = (s >= 0) && (s < HH);   // wave-uniform
#pragma unroll
            for (int j = 0; j < 4; ++j) {
                float ixx, ixy, iyy;
                if (s == 0) {            // product-field reflect: S(0)=p0+2*p1
                    ixx = hx[B2][j] + 2.0f * hx[C2][j];
                    ixy = hq[B2][j] + 2.0f * hq[C2][j];
                    iyy = hy[B2][j] + 2.0f * hy[C2][j];
                } else if (s == HH - 1) { // S(255)=2*p254+p255
                    ixx = 2.0f * hx[A][j] + hx[B2][j];
                    ixy = 2.0f * hq[A][j] + hq[B2][j];
                    iyy = 2.0f * hy[A][j] + hy[B2][j];
                } else {
                    ixx = hx[A][j] + hx[B2][j] + hx[C2][j];
                    ixy = hq[A][j] + hq[B2][j] + hq[C2][j];
                    iyy = hy[A][j] + hy[B2][j] + hy[C2][j];
                }
                float tr = ixx + iyy;
                float Rj = (ixx * iyy - ixy * ixy) - KH * tr * tr;
                Rj = vs ? Rj : NEGINF;
                R[i % 3][j] = Rj;
                rmax = fmaxf(rmax, Rj);
            }
        }

        // Rv row r = m-2 (R rows r-1,r,r+1 at slots (i+1)%3,(i+2)%3,i%3)
        if (i >= 4) {
            const int r = r0 - 4 + i;       // in [r0, r0+RS-1]
            const int A = (i + 1) % 3, B2 = (i + 2) % 3, C2 = i % 3;
            float4 o;
            o.x = fmaxf(fmaxf(R[A][0], R[B2][0]), R[C2][0]);
            o.y = fmaxf(fmaxf(R[A][1], R[B2][1]), R[C2][1]);
            o.z = fmaxf(fmaxf(R[A][2], R[B2][2]), R[C2][2]);
            o.w = fmaxf(fmaxf(R[A][3], R[B2][3]), R[C2][3]);
            *(float4*)(rb + r * WW + c0) = o;
        }
    }

    // per-slab max: block = exactly 4 slabs of one image, plain store
#pragma unroll
    for (int off = 32; off; off >>= 1) rmax = fmaxf(rmax, __shfl_xor(rmax, off));
    __shared__ float sm[4];
    if ((tid & 63) == 0) sm[tid >> 6] = rmax;
    __syncthreads();
    if (tid == 0) {
        float mm = fmaxf(fmaxf(sm[0], sm[1]), fmaxf(sm[2], sm[3]));
        ms[(img << 2) | (blockIdx.x & 3)] = mm;
    }
}

// K2: block = one (b,h) row, 512 threads / 8 waves. Xl staged via
// global_load_lds; weights via the scalar path (wave-uniform SGPR index);
// 66 KB LDS -> 2 blocks/CU. Epilogue rv loads are issued BEFORE the barrier
// so they drain concurrently with the LDS DMA (the barrier's vmcnt(0) covers
// both), and their data is consumed only after the 2048-FMA GEMV.
__global__ __launch_bounds__(512, 4) void k2(const float* __restrict__ x,
                                             const float* __restrict__ wgt,
                                             const float* __restrict__ bias,
                                             const float* __restrict__ ms,
                                             float* __restrict__ io)
{
    __shared__ __align__(16) float Xl[CH][WW];   // 64 KiB
    __shared__ float tmax[CH];
    const int tid = threadIdx.x;
    const int wv  = tid >> 6;        // wave 0..7
    const int l   = tid & 63;        // lane 0..63
    const int b   = blockIdx.x >> 8;
    const int h   = blockIdx.x & 255;
    const int oc0 = __builtin_amdgcn_readfirstlane(wv << 3);  // SGPR: wave's first out-ch

    // ---- stage x row-block into LDS via async DMA; thresholds into LDS ----
    {
        const float* xrow = x + (size_t)b * CH * HWSZ + (size_t)h * WW + (l << 2);
#pragma unroll
        for (int k = 0; k < 8; ++k) {
            __builtin_amdgcn_global_load_lds(
                (const __attribute__((address_space(1))) unsigned int*)(xrow + (size_t)(oc0 + k) * HWSZ),
                (__attribute__((address_space(3))) unsigned int*)&Xl[oc0 + k][0],
                16, 0, 0);
        }
        if (tid < CH) {
            float4 m4 = *(const float4*)(ms + ((b * CH + tid) << 2));
            tmax[tid] = TFRAC * fmaxf(fmaxf(m4.x, m4.y), fmaxf(m4.z, m4.w));
        }
    }

    // ---- issue epilogue rv loads early: drain overlaps the LDS DMA ----
    const size_t pb = (size_t)b * CH * HWSZ + (size_t)h * WW + (size_t)(l << 2);
    float4 rvv[8];
#pragma unroll
    for (int j = 0; j < 8; ++j)
        rvv[j] = *(const float4*)(io + pb + (size_t)(oc0 + j) * HWSZ);

    __syncthreads();

    // ---- conv1x1: acc[j][k] = bias + sum_ci W[oc0+j][ci] * x[ci][4l+k] ----
    float acc[8][4];
#pragma unroll
    for (int j = 0; j < 8; ++j) {
        const float bj = bias[oc0 + j];
        acc[j][0] = bj; acc[j][1] = bj; acc[j][2] = bj; acc[j][3] = bj;
    }
#pragma unroll 2
    for (int c4 = 0; c4 < CH; c4 += 4) {
        const float4 xa = *(const float4*)&Xl[c4][l << 2];
        const float4 xb = *(const float4*)&Xl[c4 + 1][l << 2];
        const float4 xc = *(const float4*)&Xl[c4 + 2][l << 2];
        const float4 xd = *(const float4*)&Xl[c4 + 3][l << 2];
#pragma unroll
        for (int j = 0; j < 8; ++j) {
            const float4 wj = *(const float4*)(wgt + (oc0 + j) * CH + c4);  // scalar load
            acc[j][0] = fmaf(wj.x, xa.x, acc[j][0]);
            acc[j][1] = fmaf(wj.x, xa.y, acc[j][1]);
            acc[j][2] = fmaf(wj.x, xa.z, acc[j][2]);
            acc[j][3] = fmaf(wj.x, xa.w, acc[j][3]);
            acc[j][0] = fmaf(wj.y, xb.x, acc[j][0]);
            acc[j][1] = fmaf(wj.y, xb.y, acc[j][1]);
            acc[j][2] = fmaf(wj.y, xb.z, acc[j][2]);
            acc[j][3] = fmaf(wj.y, xb.w, acc[j][3]);
            acc[j][0] = fmaf(wj.z, xc.x, acc[j][0]);
            acc[j][1] = fmaf(wj.z, xc.y, acc[j][1]);
            acc[j][2] = fmaf(wj.z, xc.z, acc[j][2]);
            acc[j][3] = fmaf(wj.z, xc.w, acc[j][3]);
            acc[j][0] = fmaf(wj.w, xd.x, acc[j][0]);
            acc[j][1] = fmaf(wj.w, xd.y, acc[j][1]);
            acc[j][2] = fmaf(wj.w, xd.z, acc[j][2]);
            acc[j][3] = fmaf(wj.w, xd.w, acc[j][3]);
        }
    }

    // ---- epilogue: horizontal dilate of Rv + threshold + combine ----
#pragma unroll
    for (int j = 0; j < 8; ++j) {
        const int c = oc0 + j;
        float lf = __shfl_up(rvv[j].w, 1);
        float rt = __shfl_down(rvv[j].x, 1);
        if (l == 0)  lf = NEGINF;    // col -1: border does not contribute
        if (l == 63) rt = NEGINF;    // col 256
        const float d0 = fmaxf(fmaxf(lf,       rvv[j].x), rvv[j].y);
        const float d1 = fmaxf(fmaxf(rvv[j].x, rvv[j].y), rvv[j].z);
        const float d2 = fmaxf(fmaxf(rvv[j].y, rvv[j].z), rvv[j].w);
        const float d3 = fmaxf(fmaxf(rvv[j].z, rvv[j].w), rt);
        const float t = tmax[c];
        const float4 xi = *(const float4*)&Xl[c][l << 2];
        const float y0 = fmaxf(acc[j][0], 0.0f);
        const float y1 = fmaxf(acc[j][1], 0.0f);
        const float y2 = fmaxf(acc[j][2], 0.0f);
        const float y3 = fmaxf(acc[j][3], 0.0f);
        float4 o;
        o.x = fmaf(d0 > t ? 1.0f : (d0 < t ? 0.0f : xi.x), y0, xi.x);
        o.y = fmaf(d1 > t ? 1.0f : (d1 < t ? 0.0f : xi.y), y1, xi.y);
        o.z = fmaf(d2 > t ? 1.0f : (d2 < t ? 0.0f : xi.z), y2, xi.z);
        o.w = fmaf(d3 > t ? 1.0f : (d3 < t ? 0.0f : xi.w), y3, xi.w);
        *(float4*)(io + pb + (size_t)c * HWSZ) = o;
    }
}

extern "C" void kernel_launch(void* const* d_in, const int* in_sizes, int n_in,
                              void* d_out, int out_size, void* d_ws, size_t ws_size,
                              hipStream_t stream)
{
    const float* x    = (const float*)d_in[0];
    const float* wgt  = (const float*)d_in[1];
    const float* bias = (const float*)d_in[2];
    float* out = (float*)d_out;
    float* ms = (float*)d_ws;        // NIMG*4 slab maxima (8 KiB)

    hipLaunchKernelGGL(k1, dim3(NIMG * 4), dim3(256), 0, stream, x, out, ms);
    hipLaunchKernelGGL(k2, dim3(BATCH * HH), dim3(512), 0, stream,
                       x, wgt, bias, ms, out);
}